// Round 4
// baseline (392.626 us; speedup 1.0000x reference)
//
#include <hip/hip_runtime.h>
#include <hip/hip_bf16.h>
#include <math.h>

#define BB 2
#define TT 2048
#define CC 2048
#define NH 16
#define NKV 4
#define HD 128
#define BT (BB*TT)
#define WINDOW 1024
#define SQKV 3072   // QKV buffer row stride: Q cols 0-2047, K 2048-2559, V 2560-3071

typedef unsigned short u16;
typedef unsigned int u32;
typedef __attribute__((ext_vector_type(8))) short short8;      // 8 bf16 = 4 VGPRs (MFMA A/B frag)
typedef __attribute__((ext_vector_type(8))) unsigned short ushort8;
typedef __attribute__((ext_vector_type(4))) unsigned short ushort4v;
typedef __attribute__((ext_vector_type(4))) float floatx4;     // 16x16 MFMA C/D frag
typedef __attribute__((ext_vector_type(16))) float floatx16;   // 32x32 MFMA C/D frag

typedef const __attribute__((address_space(1))) u32* gas_ptr;
typedef __attribute__((address_space(3))) u32* las_ptr;

static __device__ __forceinline__ u16 f2bf(float f) {
    unsigned u = __builtin_bit_cast(unsigned, f);
    return (u16)((u + 0x7fffu + ((u >> 16) & 1u)) >> 16);   // RNE
}
static __device__ __forceinline__ float bf2f(u16 v) {
    unsigned u = ((unsigned)v) << 16;
    return __builtin_bit_cast(float, u);
}

// fused softcap + exp: exp(50*tanh(s/50)) = exp2(72.1348 - 144.2695/(1+exp2(s*0.0577078)))
static __device__ __forceinline__ float softcap_exp(float s) {
    float z = __builtin_amdgcn_exp2f(s * 0.05770780163f);
    float r = __builtin_amdgcn_rcpf(1.0f + z);
    return __builtin_amdgcn_exp2f(fmaf(-144.269504089f, r, 72.1347520444f));
}

// ---------------- elementwise cast fp32 -> bf16 ----------------
__global__ void cast_bf16_kernel(const float* __restrict__ in, u16* __restrict__ out, int n4) {
    int i = blockIdx.x * blockDim.x + threadIdx.x;
    if (i >= n4) return;
    floatx4 v = *(const floatx4*)(in + (size_t)i * 4);
    ushort4v o;
    o[0] = f2bf(v[0]); o[1] = f2bf(v[1]); o[2] = f2bf(v[2]); o[3] = f2bf(v[3]);
    *(ushort4v*)(out + (size_t)i * 4) = o;
}

// ---------------- transpose + cast fp32 [R][Cc] -> bf16 [Cc][R] ----------------
__global__ void transpose_cast_f32_kernel(const float* __restrict__ in, u16* __restrict__ out,
                                          int R, int Cc) {
    __shared__ u16 tile[32][33];
    int c0 = blockIdx.x * 32, r0 = blockIdx.y * 32;
    int tx = threadIdx.x, ty = threadIdx.y;   // block (32, 8)
    #pragma unroll
    for (int i = 0; i < 4; i++) {
        int r = r0 + ty + i * 8;
        tile[ty + i * 8][tx] = f2bf(in[(size_t)r * Cc + c0 + tx]);
    }
    __syncthreads();
    #pragma unroll
    for (int i = 0; i < 4; i++) {
        int c = c0 + ty + i * 8;
        out[(size_t)c * R + r0 + tx] = tile[tx][ty + i * 8];
    }
}

// ---------------- strided transpose bf16: in[r][colOff + c] -> out [Cc][R], batched z ----------------
__global__ void transpose_bf16_kernel(const u16* __restrict__ in, u16* __restrict__ out,
                                      int R, int Cc, int inStride, int colOff,
                                      size_t inBatchStride, size_t outBatchStride) {
    __shared__ u16 tile[32][33];
    int b = blockIdx.z;
    const u16* inb = in + (size_t)b * inBatchStride;
    u16* outb = out + (size_t)b * outBatchStride;
    int c0 = blockIdx.y * 32, r0 = blockIdx.x * 32;
    int tx = threadIdx.x, ty = threadIdx.y;   // block (32, 8)
    #pragma unroll
    for (int i = 0; i < 4; i++) {
        int r = r0 + ty + i * 8;
        tile[ty + i * 8][tx] = inb[(size_t)r * inStride + colOff + c0 + tx];
    }
    __syncthreads();
    #pragma unroll
    for (int i = 0; i < 4; i++) {
        int c = c0 + ty + i * 8;
        outb[(size_t)c * R + r0 + tx] = tile[tx][ty + i * 8];
    }
}

// ---------------- RoPE in-place on rows of `rowStride` elems, H heads x 128, fold scale ----------------
__global__ void rope_kernel(u16* __restrict__ buf, int H, int rowStride, float scale) {
    int idx = blockIdx.x;                 // bt*H + h
    int bt = idx / H, h = idx - bt * H;
    int t = bt % TT;
    int d = threadIdx.x;                  // 0..127
    u16* p = buf + (size_t)bt * rowStride + h * HD;
    float x  = bf2f(p[d]);
    float xp = bf2f(p[d ^ 64]);
    int j = d & 63;
    float inv = exp2f(-0.20762050593046f * (float)j);   // 10000^(-j/64)
    float ang = (float)t * inv;
    float s, c;
    sincosf(ang, &s, &c);
    float rot = (d < 64) ? -xp : xp;
    float o = (x * c + rot * s) * scale;
    __syncthreads();                      // all reads done before any write
    p[d] = f2bf(o);
}

// ---------------- m97-style GEMM: C[M][N] = A[M][K] * Bt[N][K]^T (bf16 in, fp32 acc) ----------------
template <bool OUT_F32>
__global__ __launch_bounds__(256) void gemm128_kernel(const u16* __restrict__ A,
                                                      const u16* __restrict__ Bt,
                                                      void* __restrict__ Cout,
                                                      int M, int N, int K) {
    __shared__ alignas(16) u16 As[128 * 32];   // row-major [128][32], NO padding (lds-dma layout)
    __shared__ alignas(16) u16 Bs[128 * 32];
    int tid = threadIdx.x;
    int w = tid >> 6, lane = tid & 63, quad = lane >> 4, ln = lane & 15;
    int m0 = blockIdx.y * 128;
    int n0 = blockIdx.x * 128;
    int wm = (w >> 1) * 64;
    int wn = (w & 1) * 64;

    int o0 = (w * 2) * 1024 + lane * 16;
    int row0 = o0 >> 6, kc0 = (o0 & 63) >> 4;
    int o1 = o0 + 1024;
    int row1 = o1 >> 6, kc1 = (o1 & 63) >> 4;
    const u16* gA0 = A  + (size_t)(m0 + row0) * K + kc0 * 8;
    const u16* gA1 = A  + (size_t)(m0 + row1) * K + kc1 * 8;
    const u16* gB0 = Bt + (size_t)(n0 + row0) * K + kc0 * 8;
    const u16* gB1 = Bt + (size_t)(n0 + row1) * K + kc1 * 8;
    u16* lA0 = As + (w * 2) * 512;
    u16* lA1 = As + (w * 2 + 1) * 512;
    u16* lB0 = Bs + (w * 2) * 512;
    u16* lB1 = Bs + (w * 2 + 1) * 512;

    floatx4 acc[4][4] = {};

    for (int k0 = 0; k0 < K; k0 += 32) {
        __syncthreads();
        __builtin_amdgcn_global_load_lds((gas_ptr)(gA0 + k0), (las_ptr)lA0, 16, 0, 0);
        __builtin_amdgcn_global_load_lds((gas_ptr)(gA1 + k0), (las_ptr)lA1, 16, 0, 0);
        __builtin_amdgcn_global_load_lds((gas_ptr)(gB0 + k0), (las_ptr)lB0, 16, 0, 0);
        __builtin_amdgcn_global_load_lds((gas_ptr)(gB1 + k0), (las_ptr)lB1, 16, 0, 0);
        __syncthreads();

        short8 af[4], bf[4];
        #pragma unroll
        for (int mt = 0; mt < 4; mt++)
            af[mt] = *(const short8*)(As + (wm + mt * 16 + ln) * 32 + quad * 8);
        #pragma unroll
        for (int nt = 0; nt < 4; nt++)
            bf[nt] = *(const short8*)(Bs + (wn + nt * 16 + ln) * 32 + quad * 8);
        #pragma unroll
        for (int mt = 0; mt < 4; mt++)
            #pragma unroll
            for (int nt = 0; nt < 4; nt++)
                acc[mt][nt] = __builtin_amdgcn_mfma_f32_16x16x32_bf16(af[mt], bf[nt], acc[mt][nt], 0, 0, 0);
    }

    #pragma unroll
    for (int mt = 0; mt < 4; mt++)
      #pragma unroll
      for (int nt = 0; nt < 4; nt++)
        #pragma unroll
        for (int r = 0; r < 4; r++) {
            size_t row = m0 + wm + mt * 16 + quad * 4 + r;
            size_t col = n0 + wn + nt * 16 + ln;
            float v = acc[mt][nt][r];
            if (OUT_F32) ((float*)Cout)[row * N + col] = v;
            else         ((u16*)Cout)[row * N + col] = f2bf(v);
        }
}

// ---------------- flash attention: wave-independent, 32x32x16 MFMA, direct-global K/V, no barriers ----
// QKV: [B][T][3072] bf16 (Q cols 0-2047 rope'd+scaled, K cols 2048-2559 rope'd, V 2560-3071)
// Vt: [B][NKV][HD][T] bf16 ; Enc out: [B][T][NH*HD] bf16
__global__ __launch_bounds__(256) void attn_kernel(const u16* __restrict__ QKV,
                                                   const u16* __restrict__ Vt,
                                                   u16* __restrict__ Enc) {
    __shared__ alignas(16) u16 Pl[4][32][40];   // per-wave P (32 q x 32 s), pitch 40 (80B, 16B-aligned)

    int tid = threadIdx.x;
    int w = tid >> 6, lane = tid & 63, half = lane >> 5, ln = lane & 31;
    int widx = blockIdx.x * 4 + w;      // 2048 waves total
    int kqr = widx >> 5;                // 0..63
    int bh  = widx & 31;
    int b = bh >> 4, h = bh & 15;
    int kh = h >> 2;
    int kq = 63 - kqr;                  // long waves dispatch first
    int qw = kq * 32;                   // 32 queries per wave

    // Q A-frags: A[m=ln][k=half*8+j], 8 k-steps of 16 over d
    short8 qf[8];
    const u16* qptr = QKV + (size_t)(b * TT + qw + ln) * SQKV + h * HD + half * 8;
    #pragma unroll
    for (int ks = 0; ks < 8; ks++) qf[ks] = *(const short8*)(qptr + ks * 16);

    short8 ones;
    #pragma unroll
    for (int i = 0; i < 8; i++) ones[i] = (short)0x3F80;   // bf16 1.0

    floatx16 O0 = {}, O1 = {}, O2 = {}, O3 = {}, L = {};

    const u16* kbase = QKV + (size_t)b * TT * SQKV + 2048 + kh * HD + half * 8;  // + (s0+ln)*SQKV
    const u16* vbase = Vt + (size_t)(b * NKV + kh) * HD * TT;                    // + d*TT + s

    int s_lo = qw - WINDOW; if (s_lo < 0) s_lo = 0;
    int s_hi = qw + 32;

    for (int s0 = s_lo; s0 < s_hi; s0 += 32) {
        // ---- S = Q K^T (32q x 32s), K direct from global (16B contiguous per lane) ----
        const u16* krow = kbase + (size_t)(s0 + ln) * SQKV;
        floatx16 S = {};
        #pragma unroll
        for (int ks = 0; ks < 8; ks++) {
            short8 kf = *(const short8*)(krow + ks * 16);
            S = __builtin_amdgcn_mfma_f32_32x32x16_bf16(qf[ks], kf, S, 0, 0, 0);
        }

        // ---- softcap + exp (fixed-max streaming softmax) + mask on edge tiles ----
        // C layout: col s = s0+ln, row q = (r&3) + 8*(r>>2) + 4*half
        float p[16];
        bool full = (s0 + 31 <= qw) && (s0 >= qw + 31 - WINDOW);
        if (full) {
            #pragma unroll
            for (int r = 0; r < 16; r++) p[r] = softcap_exp(S[r]);
        } else {
            int s = s0 + ln;
            #pragma unroll
            for (int r = 0; r < 16; r++) {
                int t = qw + (r & 3) + 8 * (r >> 2) + 4 * half;
                bool good = (s <= t) && (s >= t - WINDOW);
                p[r] = good ? softcap_exp(S[r]) : 0.0f;
            }
        }

        // ---- P -> LDS (C-layout scatter), read back as A-frags (wave-private, no barrier) ----
        #pragma unroll
        for (int r = 0; r < 16; r++) {
            int q = (r & 3) + 8 * (r >> 2) + 4 * half;
            Pl[w][q][ln] = f2bf(p[r]);
        }
        short8 pf0 = *(const short8*)(&Pl[w][ln][half * 8]);
        short8 pf1 = *(const short8*)(&Pl[w][ln][16 + half * 8]);

        // ---- O += P V (V^T direct from global, 16B contiguous); L += P 1 ----
        const u16* vrow = vbase + (size_t)ln * TT + s0 + half * 8;
        {
            short8 vf0 = *(const short8*)(vrow);
            short8 vf1 = *(const short8*)(vrow + 16);
            O0 = __builtin_amdgcn_mfma_f32_32x32x16_bf16(pf0, vf0, O0, 0, 0, 0);
            O0 = __builtin_amdgcn_mfma_f32_32x32x16_bf16(pf1, vf1, O0, 0, 0, 0);
        }
        {
            short8 vf0 = *(const short8*)(vrow + 32 * TT);
            short8 vf1 = *(const short8*)(vrow + 32 * TT + 16);
            O1 = __builtin_amdgcn_mfma_f32_32x32x16_bf16(pf0, vf0, O1, 0, 0, 0);
            O1 = __builtin_amdgcn_mfma_f32_32x32x16_bf16(pf1, vf1, O1, 0, 0, 0);
        }
        {
            short8 vf0 = *(const short8*)(vrow + 64 * TT);
            short8 vf1 = *(const short8*)(vrow + 64 * TT + 16);
            O2 = __builtin_amdgcn_mfma_f32_32x32x16_bf16(pf0, vf0, O2, 0, 0, 0);
            O2 = __builtin_amdgcn_mfma_f32_32x32x16_bf16(pf1, vf1, O2, 0, 0, 0);
        }
        {
            short8 vf0 = *(const short8*)(vrow + 96 * TT);
            short8 vf1 = *(const short8*)(vrow + 96 * TT + 16);
            O3 = __builtin_amdgcn_mfma_f32_32x32x16_bf16(pf0, vf0, O3, 0, 0, 0);
            O3 = __builtin_amdgcn_mfma_f32_32x32x16_bf16(pf1, vf1, O3, 0, 0, 0);
        }
        L = __builtin_amdgcn_mfma_f32_32x32x16_bf16(pf0, ones, L, 0, 0, 0);
        L = __builtin_amdgcn_mfma_f32_32x32x16_bf16(pf1, ones, L, 0, 0, 0);
    }

    // ---- epilogue: normalize + store (lane owns rows q=(r&3)+8*(r>>2)+4*half at col ln) ----
    #pragma unroll
    for (int r = 0; r < 16; r++) {
        int q = (r & 3) + 8 * (r >> 2) + 4 * half;
        int t = qw + q;
        float invl = __builtin_amdgcn_rcpf(L[r]);
        u16* dst = Enc + (size_t)(b * TT + t) * (NH * HD) + h * HD + ln;
        dst[0]  = f2bf(O0[r] * invl);
        dst[32] = f2bf(O1[r] * invl);
        dst[64] = f2bf(O2[r] * invl);
        dst[96] = f2bf(O3[r] * invl);
    }
}

extern "C" void kernel_launch(void* const* d_in, const int* in_sizes, int n_in,
                              void* d_out, int out_size, void* d_ws, size_t ws_size,
                              hipStream_t stream) {
    const float* x  = (const float*)d_in[0];
    const float* wq = (const float*)d_in[1];
    const float* wk = (const float*)d_in[2];
    const float* wv = (const float*)d_in[3];
    const float* wo = (const float*)d_in[4];
    float* out = (float*)d_out;

    char* ws = (char*)d_ws;
    size_t off = 0;
    auto alloc = [&](size_t bytes) -> void* {
        void* p = ws + off;
        off += (bytes + 255) & ~(size_t)255;
        return p;
    };
    u16* xb    = (u16*)alloc((size_t)BT * CC * 2);
    u16* wqkvT = (u16*)alloc((size_t)SQKV * CC * 2);   // rows: Wq^T 0-2047, Wk^T 2048-2559, Wv^T 2560-3071
    u16* woT   = (u16*)alloc((size_t)CC * CC * 2);
    u16* QKVb  = (u16*)alloc((size_t)BT * SQKV * 2);   // [4096][3072]
    u16* VtT   = (u16*)alloc((size_t)BT * NKV * HD * 2); // [B][NKV][HD][T]
    u16* Enc   = (u16*)alloc((size_t)BT * NH * HD * 2);

    // 1) casts / weight transposes
    cast_bf16_kernel<<<(BT * CC / 4 + 255) / 256, 256, 0, stream>>>(x, xb, BT * CC / 4);
    dim3 tb(32, 8);
    transpose_cast_f32_kernel<<<dim3(CC / 32, CC / 32), tb, 0, stream>>>(wq, wqkvT, CC, CC);
    transpose_cast_f32_kernel<<<dim3(NKV * HD / 32, CC / 32), tb, 0, stream>>>(wk, wqkvT + (size_t)2048 * CC, CC, NKV * HD);
    transpose_cast_f32_kernel<<<dim3(NKV * HD / 32, CC / 32), tb, 0, stream>>>(wv, wqkvT + (size_t)2560 * CC, CC, NKV * HD);
    transpose_cast_f32_kernel<<<dim3(CC / 32, CC / 32), tb, 0, stream>>>(wo, woT, CC, CC);

    // 2) merged QKV projection (N=3072, 768 blocks)
    gemm128_kernel<false><<<dim3(SQKV / 128, BT / 128), 256, 0, stream>>>(xb, wqkvT, QKVb, BT, SQKV, CC);

    // 3) RoPE (scale folded into Q); K at col offset 2048, row stride 3072
    rope_kernel<<<BT * NH, HD, 0, stream>>>(QKVb, NH, SQKV, 0.08838834764831845f);
    rope_kernel<<<BT * NKV, HD, 0, stream>>>(QKVb + 2048, NKV, SQKV, 1.0f);

    // 4) V -> V^T per batch: QKVb cols 2560.. -> [512][T]
    transpose_bf16_kernel<<<dim3(TT / 32, NKV * HD / 32, BB), tb, 0, stream>>>(
        QKVb, VtT, TT, NKV * HD, SQKV, 2560,
        (size_t)TT * SQKV, (size_t)NKV * HD * TT);

    // 5) flash attention (2048 independent waves, 512 blocks)
    attn_kernel<<<dim3(512), 256, 0, stream>>>(QKVb, VtT, Enc);

    // 6) output projection (fp32 out)
    gemm128_kernel<true><<<dim3(CC / 128, BT / 128), 256, 0, stream>>>(Enc, woT, out, BT, CC, CC);
}